// Round 1
// baseline (635.244 us; speedup 1.0000x reference)
//
#include <hip/hip_runtime.h>
#include <stdint.h>

typedef unsigned short u16;
typedef __bf16 bf16x8 __attribute__((ext_vector_type(8)));
typedef float f32x4 __attribute__((ext_vector_type(4)));
typedef short short8v __attribute__((ext_vector_type(8)));

#define TM 128
#define BK 32
#define LDST 40   // padded leading dim (bf16 elems) to break bank conflicts

static __device__ __forceinline__ u16 f2bf(float f) {
  uint32_t u = __builtin_bit_cast(uint32_t, f);
  return (u16)((u + 0x7FFFu + ((u >> 16) & 1u)) >> 16);
}
static __device__ __forceinline__ float bf2f(u16 h) {
  uint32_t u = ((uint32_t)h) << 16;
  return __builtin_bit_cast(float, u);
}

// ---------------- fp32 -> bf16 conversion ----------------
__global__ __launch_bounds__(256) void k_f32_to_bf16(const float* __restrict__ in,
                                                     u16* __restrict__ out, int n) {
  int i = (blockIdx.x * 256 + threadIdx.x) * 4;
  if (i + 3 < n) {
    const float4 v = *(const float4*)&in[i];
    ushort4 o;
    o.x = f2bf(v.x); o.y = f2bf(v.y); o.z = f2bf(v.z); o.w = f2bf(v.w);
    *(ushort4*)&out[i] = o;
  }
}

// ---------------- shared 128x128 MFMA tile core ----------------
// A: M x K row-major; Bt: N x K row-major (i.e. B transposed).
// 256 threads = 4 waves in 2x2; each wave computes a 64x64 subtile as
// 4x4 fragments of 16x16 via v_mfma_f32_16x16x32_bf16.
// A-frag: lane reads 8 contiguous k at row (l&15), k-group (l>>4)*8.
// C/D: col = lane&15, row = (lane>>4)*4 + reg   [guide §3, m89-verified]
__device__ __forceinline__ void gemm_tile(const u16* __restrict__ A, const u16* __restrict__ Bt,
                                          int K, int lda, int ldb, long row0, long col0,
                                          u16* As, u16* Bs, f32x4 acc[4][4]) {
  const int tid = threadIdx.x;
  const int l = tid & 63;
  const int w = tid >> 6;
  const int wr = (w >> 1) * 64, wc = (w & 1) * 64;
  const int lr = l & 15, lk = (l >> 4) * 8;
  const int srow = tid >> 2, scol = (tid & 3) * 8;
  for (int k0 = 0; k0 < K; k0 += BK) {
#pragma unroll
    for (int it = 0; it < 2; ++it) {
      int r = srow + it * 64;
      *(short8v*)&As[r * LDST + scol] = *(const short8v*)&A[(row0 + r) * (long)lda + k0 + scol];
      *(short8v*)&Bs[r * LDST + scol] = *(const short8v*)&Bt[(col0 + r) * (long)ldb + k0 + scol];
    }
    __syncthreads();
    bf16x8 af[4], bfv[4];
#pragma unroll
    for (int i = 0; i < 4; ++i) {
      af[i]  = *(const bf16x8*)&As[(wr + i * 16 + lr) * LDST + lk];
      bfv[i] = *(const bf16x8*)&Bs[(wc + i * 16 + lr) * LDST + lk];
    }
#pragma unroll
    for (int mf = 0; mf < 4; ++mf)
#pragma unroll
      for (int nf = 0; nf < 4; ++nf)
        acc[mf][nf] = __builtin_amdgcn_mfma_f32_16x16x32_bf16(af[mf], bfv[nf], acc[mf][nf], 0, 0, 0);
    __syncthreads();
  }
}

#define EPI_VARS                                   \
  const int l = threadIdx.x & 63;                  \
  const int w = threadIdx.x >> 6;                  \
  const int wr = (w >> 1) * 64, wc = (w & 1) * 64; \
  const int mrow = (l >> 4) * 4, ncol = l & 15;

// ---------------- QKV projection: C = X @ W^T + b, routed to q/k/vT ----------------
__global__ __launch_bounds__(256) void k_gemm_qkv(const u16* __restrict__ X, const u16* __restrict__ W,
                                                  const float* __restrict__ bias,
                                                  u16* __restrict__ qb, u16* __restrict__ kb,
                                                  u16* __restrict__ vt, int seg, int seg_start) {
  __shared__ u16 As[TM * LDST], Bs[TM * LDST];
  f32x4 acc[4][4] = {};
  long row0 = (long)blockIdx.x * TM;
  long col0 = (long)blockIdx.y * TM;
  gemm_tile(X, W, 1024, 1024, 1024, row0, col0, As, Bs, acc);
  EPI_VARS
#pragma unroll
  for (int mf = 0; mf < 4; ++mf)
#pragma unroll
    for (int nf = 0; nf < 4; ++nf)
#pragma unroll
      for (int r = 0; r < 4; ++r) {
        int m = (int)row0 + wr + mf * 16 + mrow + r;
        int n = (int)col0 + wc + nf * 16 + ncol;
        float v = acc[mf][nf][r] + bias[n];
        int b = m / seg, s = m % seg;
        long grow = (long)b * 4608 + seg_start + s;
        if (n < 1024)       qb[grow * 1024 + n]          = f2bf(v);
        else if (n < 2048)  kb[grow * 1024 + (n - 1024)] = f2bf(v);
        else                vt[((long)b * 1024 + (n - 2048)) * 4608 + seg_start + s] = f2bf(v);
      }
}

// ---------------- RMSNorm + RoPE (in-place on q_buf / k_buf) ----------------
__global__ __launch_bounds__(256) void k_normrope(u16* __restrict__ qb, u16* __restrict__ kb,
                                                  const float* __restrict__ qsi, const float* __restrict__ ksi,
                                                  const float* __restrict__ qsc, const float* __restrict__ ksc) {
  __shared__ float sm[4];
  const int row = blockIdx.x;    // 0..9215  (b*4608 + n)
  const int which = blockIdx.y;  // 0 = q, 1 = k
  const int n = row % 4608;
  u16* buf = which ? kb : qb;
  const float* scale = which ? (n < 512 ? ksc : ksi) : (n < 512 ? qsc : qsi);
  u16* rp = buf + (long)row * 1024;
  const int t = threadIdx.x;
  float x[4];
  int idx[4];
  float ss = 0.f;
#pragma unroll
  for (int i = 0; i < 2; ++i) {
    int p = t + i * 256;                 // pair index 0..511
    int h = p >> 5, j = p & 31;          // head, rot index
    int e1 = h * 64 + j;
    idx[2 * i] = e1; idx[2 * i + 1] = e1 + 32;
    float a = bf2f(rp[e1]), b = bf2f(rp[e1 + 32]);
    x[2 * i] = a; x[2 * i + 1] = b;
    ss += a * a + b * b;
  }
#pragma unroll
  for (int o = 32; o; o >>= 1) ss += __shfl_xor(ss, o, 64);
  if ((t & 63) == 0) sm[t >> 6] = ss;
  __syncthreads();
  ss = sm[0] + sm[1] + sm[2] + sm[3];
  const float rr = rsqrtf(ss * (1.0f / 1024.0f) + 1e-6f);
#pragma unroll
  for (int i = 0; i < 2; ++i) {
    int p = t + i * 256;
    int j = p & 31;
    float x1 = x[2 * i] * rr * scale[idx[2 * i]];
    float x2 = x[2 * i + 1] * rr * scale[idx[2 * i + 1]];
    float freq = exp2f((float)j * (-13.287712379549449f / 32.0f)); // 10000^(-j/32)
    float ang = (float)n * freq;
    float sn, cs;
    sincosf(ang, &sn, &cs);
    rp[idx[2 * i]]     = f2bf(x1 * cs - x2 * sn);
    rp[idx[2 * i + 1]] = f2bf(x2 * cs + x1 * sn);
  }
}

// ---------------- S = (Q @ K^T) * 0.125  (fp32 out) ----------------
__global__ __launch_bounds__(256) void k_gemm_s(const u16* __restrict__ Q, const u16* __restrict__ Kb,
                                                float* __restrict__ S) {
  __shared__ u16 As[TM * LDST], Bs[TM * LDST];
  f32x4 acc[4][4] = {};
  long row0 = (long)blockIdx.x * TM;
  long col0 = (long)blockIdx.y * TM;
  gemm_tile(Q, Kb, 1024, 1024, 1024, row0, col0, As, Bs, acc);
  EPI_VARS
#pragma unroll
  for (int mf = 0; mf < 4; ++mf)
#pragma unroll
    for (int nf = 0; nf < 4; ++nf)
#pragma unroll
      for (int r = 0; r < 4; ++r) {
        long m = row0 + wr + mf * 16 + mrow + r;
        long n = col0 + wc + nf * 16 + ncol;
        S[m * 4608 + n] = acc[mf][nf][r] * 0.125f;
      }
}

// ---------------- row softmax: P = softmax(S row) as bf16 ----------------
__global__ __launch_bounds__(256) void k_softmax(const float* __restrict__ S, u16* __restrict__ P) {
  __shared__ float sm[4];
  const long row = blockIdx.x;
  const float* sr = S + row * 4608;
  const int t = threadIdx.x;
  float v[18];
  float mx = -3.4e38f;
#pragma unroll
  for (int i = 0; i < 18; ++i) { v[i] = sr[i * 256 + t]; mx = fmaxf(mx, v[i]); }
#pragma unroll
  for (int o = 32; o; o >>= 1) mx = fmaxf(mx, __shfl_xor(mx, o, 64));
  if ((t & 63) == 0) sm[t >> 6] = mx;
  __syncthreads();
  mx = fmaxf(fmaxf(sm[0], sm[1]), fmaxf(sm[2], sm[3]));
  __syncthreads();
  float sum = 0.f;
#pragma unroll
  for (int i = 0; i < 18; ++i) { v[i] = __expf(v[i] - mx); sum += v[i]; }
#pragma unroll
  for (int o = 32; o; o >>= 1) sum += __shfl_xor(sum, o, 64);
  if ((t & 63) == 0) sm[t >> 6] = sum;
  __syncthreads();
  sum = sm[0] + sm[1] + sm[2] + sm[3];
  const float inv = 1.0f / sum;
  u16* pr = P + row * 4608;
#pragma unroll
  for (int i = 0; i < 18; ++i) pr[i * 256 + t] = f2bf(v[i] * inv);
}

// ---------------- O = P @ V  (Bt = V^T rows) ----------------
__global__ __launch_bounds__(256) void k_gemm_o(const u16* __restrict__ P, const u16* __restrict__ VT,
                                                u16* __restrict__ AO) {
  __shared__ u16 As[TM * LDST], Bs[TM * LDST];
  f32x4 acc[4][4] = {};
  long row0 = (long)blockIdx.x * TM;
  long col0 = (long)blockIdx.y * TM;
  gemm_tile(P, VT, 4608, 4608, 4608, row0, col0, As, Bs, acc);
  EPI_VARS
#pragma unroll
  for (int mf = 0; mf < 4; ++mf)
#pragma unroll
    for (int nf = 0; nf < 4; ++nf)
#pragma unroll
      for (int r = 0; r < 4; ++r) {
        long m = row0 + wr + mf * 16 + mrow + r;
        long n = col0 + wc + nf * 16 + ncol;
        AO[m * 1024 + n] = f2bf(acc[mf][nf][r]);
      }
}

// ---------------- final projections: out = AO_seg @ W^T + b (fp32 out) ----------------
__global__ __launch_bounds__(256) void k_gemm_out(const u16* __restrict__ AO, const u16* __restrict__ W,
                                                  const float* __restrict__ bias, float* __restrict__ out,
                                                  int seg, int seg_start) {
  __shared__ u16 As[TM * LDST], Bs[TM * LDST];
  f32x4 acc[4][4] = {};
  long row0 = (long)blockIdx.x * TM;
  long col0 = (long)blockIdx.y * TM;
  long b = row0 / seg;
  const u16* Aeff = AO + ((b * 4608) + seg_start + (row0 % seg)) * 1024L;
  gemm_tile(Aeff, W, 1024, 1024, 1024, 0, col0, As, Bs, acc);
  EPI_VARS
#pragma unroll
  for (int mf = 0; mf < 4; ++mf)
#pragma unroll
    for (int nf = 0; nf < 4; ++nf)
#pragma unroll
      for (int r = 0; r < 4; ++r) {
        long m = row0 + wr + mf * 16 + mrow + r;
        long n = col0 + wc + nf * 16 + ncol;
        out[m * 1024 + n] = acc[mf][nf][r] + bias[n];
      }
}

// ---------------- launch ----------------
extern "C" void kernel_launch(void* const* d_in, const int* in_sizes, int n_in,
                              void* d_out, int out_size, void* d_ws, size_t ws_size,
                              hipStream_t stream) {
  const float* input   = (const float*)d_in[0];
  const float* context = (const float*)d_in[1];
  const float* Wqi     = (const float*)d_in[2];
  const float* bqi     = (const float*)d_in[3];
  const float* Wqc     = (const float*)d_in[4];
  const float* bqc     = (const float*)d_in[5];
  const float* qsi     = (const float*)d_in[6];
  const float* ksi     = (const float*)d_in[7];
  const float* qsc     = (const float*)d_in[8];
  const float* ksc     = (const float*)d_in[9];
  const float* Woi     = (const float*)d_in[10];
  const float* boi     = (const float*)d_in[11];
  const float* Woc     = (const float*)d_in[12];
  const float* boc     = (const float*)d_in[13];
  float* out = (float*)d_out;

  uint8_t* ws = (uint8_t*)d_ws;
  // workspace layout (bytes)
  u16* XIN  = (u16*)(ws + 0);            // 2*4096*1024 bf16       = 16,777,216
  u16* XCTX = (u16*)(ws + 16777216);     // 2*512*1024             =  2,097,152
  u16* WQI  = (u16*)(ws + 18874368);     // 3072*1024              =  6,291,456
  u16* WQC  = (u16*)(ws + 25165824);     // 3072*1024              =  6,291,456
  u16* WOI  = (u16*)(ws + 31457280);     // 1024*1024              =  2,097,152
  u16* WOC  = (u16*)(ws + 33554432);     // 1024*1024              =  2,097,152
  u16* QB   = (u16*)(ws + 35651584);     // 2*4608*1024            = 18,874,368
  u16* KB   = (u16*)(ws + 54525952);     // 2*4608*1024            = 18,874,368
  u16* VT   = (u16*)(ws + 73400320);     // 2*1024*4608            = 18,874,368
  u16* AO   = (u16*)(ws + 92274688);     // 2*4608*1024            = 18,874,368
  float* S32 = (float*)(ws + 111149056); // 4608*4608 fp32 (per-batch, reused) = 84,934,656
  u16* PB   = (u16*)(ws + 196083712);    // 4608*4608 bf16 (per-batch, reused) = 42,467,328
  // total = 238,551,040 bytes

  // fp32 -> bf16 conversions
  k_f32_to_bf16<<<dim3(8192), 256, 0, stream>>>(input, XIN, 2 * 4096 * 1024);
  k_f32_to_bf16<<<dim3(1024), 256, 0, stream>>>(context, XCTX, 2 * 512 * 1024);
  k_f32_to_bf16<<<dim3(3072), 256, 0, stream>>>(Wqi, WQI, 3072 * 1024);
  k_f32_to_bf16<<<dim3(3072), 256, 0, stream>>>(Wqc, WQC, 3072 * 1024);
  k_f32_to_bf16<<<dim3(1024), 256, 0, stream>>>(Woi, WOI, 1024 * 1024);
  k_f32_to_bf16<<<dim3(1024), 256, 0, stream>>>(Woc, WOC, 1024 * 1024);

  // QKV projections (writes q,k pre-norm; v transposed)
  k_gemm_qkv<<<dim3(64, 24), 256, 0, stream>>>(XIN, WQI, bqi, QB, KB, VT, 4096, 512);
  k_gemm_qkv<<<dim3(8, 24), 256, 0, stream>>>(XCTX, WQC, bqc, QB, KB, VT, 512, 0);

  // RMSNorm + RoPE in place on q,k
  k_normrope<<<dim3(9216, 2), 256, 0, stream>>>(QB, KB, qsi, ksi, qsc, ksc);

  // attention, one batch at a time (S/P buffers reused)
  for (int b = 0; b < 2; ++b) {
    const u16* Qb = QB + (long)b * 4608 * 1024;
    const u16* Kbp = KB + (long)b * 4608 * 1024;
    const u16* VTb = VT + (long)b * 1024 * 4608;
    u16* AOb = AO + (long)b * 4608 * 1024;
    k_gemm_s<<<dim3(36, 36), 256, 0, stream>>>(Qb, Kbp, S32);
    k_softmax<<<dim3(4608), 256, 0, stream>>>(S32, PB);
    k_gemm_o<<<dim3(36, 8), 256, 0, stream>>>(PB, VTb, AOb);
  }

  // output projections
  k_gemm_out<<<dim3(64, 8), 256, 0, stream>>>(AO, WOI, boi, out, 4096, 512);
  k_gemm_out<<<dim3(8, 8), 256, 0, stream>>>(AO, WOC, boc, out + 8388608, 512, 0);
}

// Round 2
// 556.428 us; speedup vs baseline: 1.1416x; 1.1416x over previous
//
#include <hip/hip_runtime.h>
#include <stdint.h>

typedef unsigned short u16;
typedef __bf16 bf16x8 __attribute__((ext_vector_type(8)));
typedef float f32x4 __attribute__((ext_vector_type(4)));

#define TM 128
#define BK 32

typedef const __attribute__((address_space(1))) uint32_t* gu32p;
typedef __attribute__((address_space(3))) uint32_t* lu32p;
#define GLOAD_LDS16(g, l) \
  __builtin_amdgcn_global_load_lds((gu32p)(const void*)(g), (lu32p)(void*)(l), 16, 0, 0)

static __device__ __forceinline__ u16 f2bf(float f) {
  uint32_t u = __builtin_bit_cast(uint32_t, f);
  return (u16)((u + 0x7FFFu + ((u >> 16) & 1u)) >> 16);
}
static __device__ __forceinline__ float bf2f(u16 h) {
  uint32_t u = ((uint32_t)h) << 16;
  return __builtin_bit_cast(float, u);
}

// ---------------- fp32 -> bf16 conversion ----------------
__global__ __launch_bounds__(256) void k_f32_to_bf16(const float* __restrict__ in,
                                                     u16* __restrict__ out, int n) {
  int i = (blockIdx.x * 256 + threadIdx.x) * 4;
  if (i + 3 < n) {
    const float4 v = *(const float4*)&in[i];
    ushort4 o;
    o.x = f2bf(v.x); o.y = f2bf(v.y); o.z = f2bf(v.z); o.w = f2bf(v.w);
    *(ushort4*)&out[i] = o;
  }
}

// ---------------- shared 128x128 MFMA tile core (m97 structure) ----------------
// A: M x K row-major; Bt: N x K row-major. 256 threads = 4 waves (2x2),
// each wave computes 64x64 as 4x4 frags of 16x16x32 MFMA.
// Staging: global_load_lds width=16 into LINEAR [128][32] LDS tiles.
// LDS chunk c (1024B) = rows [c*16, c*16+16); wave w stages chunks 2w, 2w+1.
__device__ __forceinline__ void gemm_tile(const u16* __restrict__ A, const u16* __restrict__ Bt,
                                          int lda, int ldb, long row0, long col0,
                                          int k_begin, int k_end,
                                          u16* As, u16* Bs, f32x4 acc[4][4]) {
  const int tid = threadIdx.x;
  const int l = tid & 63;
  const int w = tid >> 6;
  const int wr = (w >> 1) * 64, wc = (w & 1) * 64;
  const int lr = l & 15, lk = (l >> 4) * 8;
  const int c0 = w * 2;
  const int sr = c0 * 16 + (l >> 2);   // staging row for issue 0
  const int sc = (l & 3) * 8;          // staging col (elems)
  u16* As0 = As + c0 * 512;            // wave-uniform LDS dests (elems)
  u16* Bs0 = Bs + c0 * 512;
  const u16* pa = &A[(row0 + sr) * (long)lda + sc];
  const u16* pb = &Bt[(col0 + sr) * (long)ldb + sc];
  for (int k0 = k_begin; k0 < k_end; k0 += BK) {
    GLOAD_LDS16(pa + k0, As0);
    GLOAD_LDS16(pa + 16 * (long)lda + k0, As0 + 512);
    GLOAD_LDS16(pb + k0, Bs0);
    GLOAD_LDS16(pb + 16 * (long)ldb + k0, Bs0 + 512);
    __syncthreads();
    bf16x8 af[4], bfv[4];
#pragma unroll
    for (int i = 0; i < 4; ++i) {
      af[i]  = *(const bf16x8*)&As[(wr + i * 16 + lr) * BK + lk];
      bfv[i] = *(const bf16x8*)&Bs[(wc + i * 16 + lr) * BK + lk];
    }
#pragma unroll
    for (int mf = 0; mf < 4; ++mf)
#pragma unroll
      for (int nf = 0; nf < 4; ++nf)
        acc[mf][nf] = __builtin_amdgcn_mfma_f32_16x16x32_bf16(af[mf], bfv[nf], acc[mf][nf], 0, 0, 0);
    __syncthreads();
  }
}

#define EPI_VARS                                   \
  const int l = threadIdx.x & 63;                  \
  const int w = threadIdx.x >> 6;                  \
  const int wr = (w >> 1) * 64, wc = (w & 1) * 64; \
  const int mrow = (l >> 4) * 4, ncol = l & 15;

// ---------------- QKV projection: C = X @ W^T + b, routed to q/k/vT ----------------
__global__ __launch_bounds__(256) void k_gemm_qkv(const u16* __restrict__ X, const u16* __restrict__ W,
                                                  const float* __restrict__ bias,
                                                  u16* __restrict__ qb, u16* __restrict__ kb,
                                                  u16* __restrict__ vt, int seg, int seg_start) {
  __shared__ u16 As[TM * BK], Bs[TM * BK];
  f32x4 acc[4][4] = {};
  long row0 = (long)blockIdx.x * TM;
  long col0 = (long)blockIdx.y * TM;
  gemm_tile(X, W, 1024, 1024, row0, col0, 0, 1024, As, Bs, acc);
  EPI_VARS
#pragma unroll
  for (int mf = 0; mf < 4; ++mf)
#pragma unroll
    for (int nf = 0; nf < 4; ++nf)
#pragma unroll
      for (int r = 0; r < 4; ++r) {
        int m = (int)row0 + wr + mf * 16 + mrow + r;
        int n = (int)col0 + wc + nf * 16 + ncol;
        float v = acc[mf][nf][r] + bias[n];
        int b = m / seg, s = m % seg;
        long grow = (long)b * 4608 + seg_start + s;
        if (n < 1024)       qb[grow * 1024 + n]          = f2bf(v);
        else if (n < 2048)  kb[grow * 1024 + (n - 1024)] = f2bf(v);
        else                vt[((long)b * 1024 + (n - 2048)) * 4608 + seg_start + s] = f2bf(v);
      }
}

// ---------------- RMSNorm + RoPE (in-place on q_buf / k_buf) ----------------
__global__ __launch_bounds__(256) void k_normrope(u16* __restrict__ qb, u16* __restrict__ kb,
                                                  const float* __restrict__ qsi, const float* __restrict__ ksi,
                                                  const float* __restrict__ qsc, const float* __restrict__ ksc) {
  __shared__ float sm[4];
  const int row = blockIdx.x;    // 0..9215  (b*4608 + n)
  const int which = blockIdx.y;  // 0 = q, 1 = k
  const int n = row % 4608;
  u16* buf = which ? kb : qb;
  const float* scale = which ? (n < 512 ? ksc : ksi) : (n < 512 ? qsc : qsi);
  u16* rp = buf + (long)row * 1024;
  const int t = threadIdx.x;
  float x[4];
  int idx[4];
  float ss = 0.f;
#pragma unroll
  for (int i = 0; i < 2; ++i) {
    int p = t + i * 256;                 // pair index 0..511
    int h = p >> 5, j = p & 31;          // head, rot index
    int e1 = h * 64 + j;
    idx[2 * i] = e1; idx[2 * i + 1] = e1 + 32;
    float a = bf2f(rp[e1]), b = bf2f(rp[e1 + 32]);
    x[2 * i] = a; x[2 * i + 1] = b;
    ss += a * a + b * b;
  }
#pragma unroll
  for (int o = 32; o; o >>= 1) ss += __shfl_xor(ss, o, 64);
  if ((t & 63) == 0) sm[t >> 6] = ss;
  __syncthreads();
  ss = sm[0] + sm[1] + sm[2] + sm[3];
  const float rr = rsqrtf(ss * (1.0f / 1024.0f) + 1e-6f);
#pragma unroll
  for (int i = 0; i < 2; ++i) {
    int p = t + i * 256;
    int j = p & 31;
    float x1 = x[2 * i] * rr * scale[idx[2 * i]];
    float x2 = x[2 * i + 1] * rr * scale[idx[2 * i + 1]];
    float freq = exp2f((float)j * (-13.287712379549449f / 32.0f)); // 10000^(-j/32)
    float ang = (float)n * freq;
    float sn, cs;
    sincosf(ang, &sn, &cs);
    rp[idx[2 * i]]     = f2bf(x1 * cs - x2 * sn);
    rp[idx[2 * i + 1]] = f2bf(x2 * cs + x1 * sn);
  }
}

// ---------------- S = (Q @ K^T) * 0.125  (fp32 out) ----------------
__global__ __launch_bounds__(256) void k_gemm_s(const u16* __restrict__ Q, const u16* __restrict__ Kb,
                                                float* __restrict__ S) {
  __shared__ u16 As[TM * BK], Bs[TM * BK];
  f32x4 acc[4][4] = {};
  long row0 = (long)blockIdx.x * TM;
  long col0 = (long)blockIdx.y * TM;
  gemm_tile(Q, Kb, 1024, 1024, row0, col0, 0, 1024, As, Bs, acc);
  EPI_VARS
#pragma unroll
  for (int mf = 0; mf < 4; ++mf)
#pragma unroll
    for (int nf = 0; nf < 4; ++nf)
#pragma unroll
      for (int r = 0; r < 4; ++r) {
        long m = row0 + wr + mf * 16 + mrow + r;
        long n = col0 + wc + nf * 16 + ncol;
        S[m * 4608 + n] = acc[mf][nf][r] * 0.125f;
      }
}

// ---------------- row softmax: P = softmax(S row) as bf16 ----------------
__global__ __launch_bounds__(256) void k_softmax(const float* __restrict__ S, u16* __restrict__ P) {
  __shared__ float sm[4];
  const long row = blockIdx.x;
  const float* sr = S + row * 4608;
  const int t = threadIdx.x;
  float v[18];
  float mx = -3.4e38f;
#pragma unroll
  for (int i = 0; i < 18; ++i) { v[i] = sr[i * 256 + t]; mx = fmaxf(mx, v[i]); }
#pragma unroll
  for (int o = 32; o; o >>= 1) mx = fmaxf(mx, __shfl_xor(mx, o, 64));
  if ((t & 63) == 0) sm[t >> 6] = mx;
  __syncthreads();
  mx = fmaxf(fmaxf(sm[0], sm[1]), fmaxf(sm[2], sm[3]));
  __syncthreads();
  float sum = 0.f;
#pragma unroll
  for (int i = 0; i < 18; ++i) { v[i] = __expf(v[i] - mx); sum += v[i]; }
#pragma unroll
  for (int o = 32; o; o >>= 1) sum += __shfl_xor(sum, o, 64);
  if ((t & 63) == 0) sm[t >> 6] = sum;
  __syncthreads();
  sum = sm[0] + sm[1] + sm[2] + sm[3];
  const float inv = 1.0f / sum;
  u16* pr = P + row * 4608;
#pragma unroll
  for (int i = 0; i < 18; ++i) pr[i * 256 + t] = f2bf(v[i] * inv);
}

// ---------------- O partials = P @ V (split-K over z), fp32 out ----------------
__global__ __launch_bounds__(256) void k_gemm_o_splitk(const u16* __restrict__ P, const u16* __restrict__ VT,
                                                       float* __restrict__ OP) {
  __shared__ u16 As[TM * BK], Bs[TM * BK];
  f32x4 acc[4][4] = {};
  long row0 = (long)blockIdx.x * TM;
  long col0 = (long)blockIdx.y * TM;
  const int kc = blockIdx.z;           // 0..3, K chunk of 1152
  gemm_tile(P, VT, 4608, 4608, row0, col0, kc * 1152, (kc + 1) * 1152, As, Bs, acc);
  float* op = OP + (long)kc * 4608 * 1024;
  EPI_VARS
#pragma unroll
  for (int mf = 0; mf < 4; ++mf)
#pragma unroll
    for (int nf = 0; nf < 4; ++nf)
#pragma unroll
      for (int r = 0; r < 4; ++r) {
        long m = row0 + wr + mf * 16 + mrow + r;
        long n = col0 + wc + nf * 16 + ncol;
        op[m * 1024 + n] = acc[mf][nf][r];
      }
}

// ---------------- reduce 4 fp32 partials -> bf16 AO ----------------
__global__ __launch_bounds__(256) void k_reduce4(const float* __restrict__ OP, u16* __restrict__ AO) {
  const long st = 4608L * 1024;
  long i = ((long)blockIdx.x * 256 + threadIdx.x) * 4;
  float4 a = *(const float4*)&OP[i];
  float4 b = *(const float4*)&OP[i + st];
  float4 c = *(const float4*)&OP[i + 2 * st];
  float4 d = *(const float4*)&OP[i + 3 * st];
  ushort4 o;
  o.x = f2bf(a.x + b.x + c.x + d.x);
  o.y = f2bf(a.y + b.y + c.y + d.y);
  o.z = f2bf(a.z + b.z + c.z + d.z);
  o.w = f2bf(a.w + b.w + c.w + d.w);
  *(ushort4*)&AO[i] = o;
}

// ---------------- merged output projections: out = AO @ W^T + b (fp32 out) ----------------
__global__ __launch_bounds__(256) void k_gemm_out2(const u16* __restrict__ AO,
                                                   const u16* __restrict__ WOI, const u16* __restrict__ WOC,
                                                   const float* __restrict__ boi, const float* __restrict__ boc,
                                                   float* __restrict__ out) {
  __shared__ u16 As[TM * BK], Bs[TM * BK];
  f32x4 acc[4][4] = {};
  long row0 = (long)blockIdx.x * TM;      // global row in [0,9216)
  long col0 = (long)blockIdx.y * TM;
  int b = (int)(row0 / 4608);
  int s0 = (int)(row0 % 4608);
  const bool ctx = s0 < 512;              // 512 % 128 == 0 -> uniform per block
  const u16* W = ctx ? WOC : WOI;
  const float* bias = ctx ? boc : boi;
  float* ob = ctx ? out + 8388608 + ((long)b * 512 + s0) * 1024
                  : out + ((long)b * 4096 + (s0 - 512)) * 1024;
  gemm_tile(AO, W, 1024, 1024, row0, col0, 0, 1024, As, Bs, acc);
  EPI_VARS
#pragma unroll
  for (int mf = 0; mf < 4; ++mf)
#pragma unroll
    for (int nf = 0; nf < 4; ++nf)
#pragma unroll
      for (int r = 0; r < 4; ++r) {
        long m = wr + mf * 16 + mrow + r;           // local row within tile
        long n = col0 + wc + nf * 16 + ncol;
        ob[m * 1024 + n] = acc[mf][nf][r] + bias[n];
      }
}

// ---------------- launch ----------------
extern "C" void kernel_launch(void* const* d_in, const int* in_sizes, int n_in,
                              void* d_out, int out_size, void* d_ws, size_t ws_size,
                              hipStream_t stream) {
  const float* input   = (const float*)d_in[0];
  const float* context = (const float*)d_in[1];
  const float* Wqi     = (const float*)d_in[2];
  const float* bqi     = (const float*)d_in[3];
  const float* Wqc     = (const float*)d_in[4];
  const float* bqc     = (const float*)d_in[5];
  const float* qsi     = (const float*)d_in[6];
  const float* ksi     = (const float*)d_in[7];
  const float* qsc     = (const float*)d_in[8];
  const float* ksc     = (const float*)d_in[9];
  const float* Woi     = (const float*)d_in[10];
  const float* boi     = (const float*)d_in[11];
  const float* Woc     = (const float*)d_in[12];
  const float* boc     = (const float*)d_in[13];
  float* out = (float*)d_out;

  uint8_t* ws = (uint8_t*)d_ws;
  // workspace layout (bytes)
  u16* XIN  = (u16*)(ws + 0);            // 2*4096*1024 bf16       = 16,777,216
  u16* XCTX = (u16*)(ws + 16777216);     // 2*512*1024             =  2,097,152
  u16* WQI  = (u16*)(ws + 18874368);     // 3072*1024              =  6,291,456
  u16* WQC  = (u16*)(ws + 25165824);     // 3072*1024              =  6,291,456
  u16* WOI  = (u16*)(ws + 31457280);     // 1024*1024              =  2,097,152
  u16* WOC  = (u16*)(ws + 33554432);     // 1024*1024              =  2,097,152
  u16* QB   = (u16*)(ws + 35651584);     // 2*4608*1024            = 18,874,368
  u16* KB   = (u16*)(ws + 54525952);     // 2*4608*1024            = 18,874,368
  u16* VT   = (u16*)(ws + 73400320);     // 2*1024*4608            = 18,874,368
  u16* AO   = (u16*)(ws + 92274688);     // 2*4608*1024            = 18,874,368
  float* S32 = (float*)(ws + 111149056); // 4608*4608 fp32 (per-batch; also 4x fp32 O-partials) = 84,934,656
  u16* PB   = (u16*)(ws + 196083712);    // 4608*4608 bf16 (per-batch, reused) = 42,467,328
  // total = 238,551,040 bytes

  // fp32 -> bf16 conversions
  k_f32_to_bf16<<<dim3(8192), 256, 0, stream>>>(input, XIN, 2 * 4096 * 1024);
  k_f32_to_bf16<<<dim3(1024), 256, 0, stream>>>(context, XCTX, 2 * 512 * 1024);
  k_f32_to_bf16<<<dim3(3072), 256, 0, stream>>>(Wqi, WQI, 3072 * 1024);
  k_f32_to_bf16<<<dim3(3072), 256, 0, stream>>>(Wqc, WQC, 3072 * 1024);
  k_f32_to_bf16<<<dim3(1024), 256, 0, stream>>>(Woi, WOI, 1024 * 1024);
  k_f32_to_bf16<<<dim3(1024), 256, 0, stream>>>(Woc, WOC, 1024 * 1024);

  // QKV projections (writes q,k pre-norm; v transposed)
  k_gemm_qkv<<<dim3(64, 24), 256, 0, stream>>>(XIN, WQI, bqi, QB, KB, VT, 4096, 512);
  k_gemm_qkv<<<dim3(8, 24), 256, 0, stream>>>(XCTX, WQC, bqc, QB, KB, VT, 512, 0);

  // RMSNorm + RoPE in place on q,k
  k_normrope<<<dim3(9216, 2), 256, 0, stream>>>(QB, KB, qsi, ksi, qsc, ksc);

  // attention, one batch at a time (S/P buffers reused; O-partials alias S32)
  for (int b = 0; b < 2; ++b) {
    const u16* Qb  = QB + (long)b * 4608 * 1024;
    const u16* Kbp = KB + (long)b * 4608 * 1024;
    const u16* VTb = VT + (long)b * 1024 * 4608;
    u16* AOb = AO + (long)b * 4608 * 1024;
    k_gemm_s<<<dim3(36, 36), 256, 0, stream>>>(Qb, Kbp, S32);
    k_softmax<<<dim3(4608), 256, 0, stream>>>(S32, PB);
    k_gemm_o_splitk<<<dim3(36, 8, 4), 256, 0, stream>>>(PB, VTb, (float*)S32);
    k_reduce4<<<dim3(4608), 256, 0, stream>>>((const float*)S32, AOb);
  }

  // merged output projections
  k_gemm_out2<<<dim3(72, 8), 256, 0, stream>>>(AO, WOI, WOC, boi, boc, out);
}